// Round 4
// baseline (1287.056 us; speedup 1.0000x reference)
//
#include <hip/hip_runtime.h>
#include <hip/hip_bf16.h>
#include <stdint.h>

typedef _Float16 f16x8 __attribute__((ext_vector_type(8)));
typedef float    f32x4 __attribute__((ext_vector_type(4)));

// async 16-B global->LDS DMA: per-lane global src, dest = wave-uniform base + lane*16
#define GLDS16(gptr, lptr) \
  __builtin_amdgcn_global_load_lds((const __attribute__((address_space(1))) void*)(gptr), \
                                   (__attribute__((address_space(3))) void*)(lptr), 16, 0, 0)

// WP layout: [c(8)][d0b(4)][g(4)][sub(8)][nl(64)][j(8)] halves.
// element = W(group g, dim d = d0b*64+nl, k = c*64+sub*8+j)
// Block 2048 packs BC[1024]: [d]=bih[d]+bhh[d], [256+d]=bih[256+d]+bhh[256+d],
//                            [512+d]=bih[512+d], [768+d]=bhh[512+d]
__global__ __launch_bounds__(256) void prepack_weights(
    const float* __restrict__ Wih, const float* __restrict__ Whh,
    const float* __restrict__ bih, const float* __restrict__ bhh,
    _Float16* __restrict__ WP, float* __restrict__ BC)
{
    if (blockIdx.x == 2048) {
        int i = threadIdx.x;
        BC[i]       = bih[i] + bhh[i];
        BC[256 + i] = bih[256 + i] + bhh[256 + i];
        BC[512 + i] = bih[512 + i];
        BC[768 + i] = bhh[512 + i];
        return;
    }
    int idx = blockIdx.x * 256 + threadIdx.x;   // 524288 total
    int j   = idx & 7;
    int nl  = (idx >> 3) & 63;
    int sub = (idx >> 9) & 7;
    int g   = (idx >> 12) & 3;
    int d0b = (idx >> 14) & 3;
    int c   = idx >> 16;
    int k = c * 64 + sub * 8 + j;
    int d = d0b * 64 + nl;
    float v = 0.f;
    if (g == 0)      v = (k < 256) ? Wih[d * 256 + k]         : Whh[d * 256 + (k - 256)];
    else if (g == 1) v = (k < 256) ? Wih[(256 + d) * 256 + k] : Whh[(256 + d) * 256 + (k - 256)];
    else if (g == 2) v = (k < 256) ? Wih[(512 + d) * 256 + k] : 0.f;
    else             v = (k >= 256) ? Whh[(512 + d) * 256 + (k - 256)] : 0.f;
    WP[idx] = (_Float16)v;
}

// fp32 leaf -> fp16, split even/odd rows (xL / xR contiguous)
__global__ __launch_bounds__(256) void convert_split(
    const float* __restrict__ leaf, _Float16* __restrict__ XE, _Float16* __restrict__ XO)
{
    int t = blockIdx.x * 256 + threadIdx.x;
    size_t e = (size_t)t * 4;
    int row = (int)(e >> 8), col = (int)(e & 255);
    float4 v = *(const float4*)(leaf + e);
    _Float16* dst = ((row & 1) ? XO : XE) + ((size_t)(row >> 1) * 256 + col);
    union { _Float16 h[4]; uint64_t u; } p;
    p.h[0] = (_Float16)v.x; p.h[1] = (_Float16)v.y;
    p.h[2] = (_Float16)v.z; p.h[3] = (_Float16)v.w;
    *(uint64_t*)dst = p.u;
}

// GRU cell. A-fragments: direct global->register (L1 serves the 4-wave re-read).
// B (weights): LDS via async DMA, double-buffered, ONE barrier per chunk.
// cell1 (Hout != null): h' -> Hout[m]        (hin = Hsrc[m] or 0)
// cell2 (Hout == null): E=0.5(hin+h') -> Ee/Eo split; HP[m/2] = pair-avg(h')
template<int MT, bool SWIZ>
__global__ __launch_bounds__(256, 3) void gru_cell(
    const _Float16* __restrict__ Xsrc,
    const _Float16* __restrict__ Hsrc,
    const _Float16* __restrict__ WP,
    const float* __restrict__ BC,
    _Float16* __restrict__ Hout,
    _Float16* __restrict__ Ee, _Float16* __restrict__ Eo, _Float16* __restrict__ HP,
    int M)
{
    constexpr int BROW = 520;               // 64*8 + 8 pad (bank shift per sub-row)
    constexpr int BSZ  = 3 * 8 * BROW;      // one buffer: 24.4 KB
    __shared__ __align__(16) _Float16 Blds[2 * BSZ];   // 49.9 KB -> 3 blocks/CU

    const int tid  = threadIdx.x;
    int bm, d0b;
    if (SWIZ) {  // siblings (same bm, 4 d0b) share blockIdx%8 -> same XCD
        int xcd = blockIdx.x & 7, slot = blockIdx.x >> 3;
        d0b = slot & 3;
        bm  = (slot >> 2) * 8 + xcd;
    } else {
        bm = blockIdx.x >> 2; d0b = blockIdx.x & 3;
    }
    const int m0   = bm * (MT * 16);
    const int tidw = tid;
    const int wave = tidw >> 6, lane = tidw & 63;
    const int quad = lane >> 4, lo = lane & 15;

    const bool has_h = (Hsrc != nullptr);
    const int nch = has_h ? 8 : 4;

    f32x4 acc[MT][4];
#pragma unroll
    for (int a = 0; a < MT; ++a)
#pragma unroll
        for (int b = 0; b < 4; ++b) acc[a][b] = (f32x4){0.f, 0.f, 0.f, 0.f};

    auto issueB = [&](int c) {   // 24 DMA issues (3 active groups x 8 subs), 6/wave
        const size_t cb = (size_t)(c * 4 + d0b) * 4;
        _Float16* dstb = Blds + (c & 1) * BSZ;
#pragma unroll
        for (int i = 0; i < 6; ++i) {
            int bi = wave * 6 + i;
            int slot = bi >> 3, sub = bi & 7;
            int g = (slot == 2) ? ((c < 4) ? 2 : 3) : slot;
            GLDS16(WP + ((cb + g) * 8 + sub) * 512 + lane * 8,
                   dstb + (slot * 8 + sub) * BROW);
        }
    };

    issueB(0);

    for (int c = 0; c < nch; ++c) {
        __syncthreads();                  // drains B(c); frees other buffer
        if (c + 1 < nch) issueB(c + 1);   // in flight during compute(c)

        const _Float16* Bb = Blds + (c & 1) * BSZ;
        const _Float16* abase = ((c < 4) ? Xsrc : Hsrc) + (size_t)(c & 3) * 64 + quad * 8;
#pragma unroll
        for (int ks = 0; ks < 2; ++ks) {
            const int subb = ks * 4 + quad;
            const _Float16* brow = Bb + subb * BROW + (wave * 16 + lo) * 8;
            f16x8 b0 = *(const f16x8*)(brow);
            f16x8 b1 = *(const f16x8*)(brow + 8 * BROW);
            f16x8 b2 = *(const f16x8*)(brow + 16 * BROW);
            const _Float16* ak = abase + ks * 32;
            if (c < 4) {
#pragma unroll
                for (int mt = 0; mt < MT; ++mt) {
                    int row = m0 + mt * 16 + lo;
                    if (MT == 4 && row >= M) row = M - 1;
                    f16x8 af = *(const f16x8*)(ak + (size_t)row * 256);
                    acc[mt][0] = __builtin_amdgcn_mfma_f32_16x16x32_f16(af, b0, acc[mt][0], 0, 0, 0);
                    acc[mt][1] = __builtin_amdgcn_mfma_f32_16x16x32_f16(af, b1, acc[mt][1], 0, 0, 0);
                    acc[mt][2] = __builtin_amdgcn_mfma_f32_16x16x32_f16(af, b2, acc[mt][2], 0, 0, 0);
                }
            } else {
#pragma unroll
                for (int mt = 0; mt < MT; ++mt) {
                    int row = m0 + mt * 16 + lo;
                    if (MT == 4 && row >= M) row = M - 1;
                    f16x8 af = *(const f16x8*)(ak + (size_t)row * 256);
                    acc[mt][0] = __builtin_amdgcn_mfma_f32_16x16x32_f16(af, b0, acc[mt][0], 0, 0, 0);
                    acc[mt][1] = __builtin_amdgcn_mfma_f32_16x16x32_f16(af, b1, acc[mt][1], 0, 0, 0);
                    acc[mt][3] = __builtin_amdgcn_mfma_f32_16x16x32_f16(af, b2, acc[mt][3], 0, 0, 0);
                }
            }
        }
    }

    // ---- epilogue (Hsrc read direct from global; L1-hot from chunk c=4+d0b) ----
    const int d = d0b * 64 + wave * 16 + lo;
    const float brz0 = BC[d];        // bir+bhr
    const float brz1 = BC[256 + d];  // biz+bhz
    const float bni  = BC[512 + d];  // bin
    const float bnh  = BC[768 + d];  // bhn
#pragma unroll
    for (int mt = 0; mt < MT; ++mt) {
        const int mbase = m0 + mt * 16 + quad * 4;
        float hq[4], h1v[4];
#pragma unroll
        for (int r = 0; r < 4; ++r) {
            int m = mbase + r;
            int mm = (MT == 8) ? m : ((m < M) ? m : (M - 1));
            float hin = has_h ? (float)Hsrc[(size_t)mm * 256 + d] : 0.f;
            h1v[r] = hin;
            float rg = 1.f / (1.f + __expf(-(acc[mt][0][r] + brz0)));
            float zg = 1.f / (1.f + __expf(-(acc[mt][1][r] + brz1)));
            float ex = __expf(2.f * (acc[mt][2][r] + bni + rg * (acc[mt][3][r] + bnh)));
            float nv = 1.f - 2.f / (ex + 1.f);
            hq[r] = (1.f - zg) * nv + zg * hin;
        }
        if (Hout) {
#pragma unroll
            for (int r = 0; r < 4; ++r)
                if (MT == 8 || mbase + r < M)
                    Hout[(size_t)(mbase + r) * 256 + d] = (_Float16)hq[r];
        } else {
#pragma unroll
            for (int r = 0; r < 4; ++r) {
                int m = mbase + r;
                if (MT == 8 || m < M)
                    (((m & 1) ? Eo : Ee))[(size_t)(m >> 1) * 256 + d] =
                        (_Float16)(0.5f * (h1v[r] + hq[r]));
            }
            if (MT == 8 || mbase + 1 < M)
                HP[(size_t)(mbase >> 1) * 256 + d] = (_Float16)(0.5f * (hq[0] + hq[1]));
            if (MT == 8 || mbase + 3 < M)
                HP[(size_t)((mbase >> 1) + 1) * 256 + d] = (_Float16)(0.5f * (hq[2] + hq[3]));
        }
    }
}

__global__ __launch_bounds__(256) void final_out(
    const _Float16* __restrict__ XE, const _Float16* __restrict__ XO,
    float* __restrict__ out)
{
    int i = blockIdx.x * 256 + threadIdx.x;   // 8192
    int j = i >> 8, col = i & 255;
    const _Float16* src = (j & 1) ? XO : XE;
    out[i] = (float)src[(size_t)(j >> 1) * 256 + col];
}

extern "C" void kernel_launch(void* const* d_in, const int* in_sizes, int n_in,
                              void* d_out, int out_size, void* d_ws, size_t ws_size,
                              hipStream_t stream) {
    const float* leaf = (const float*)d_in[0];
    const float* Wih  = (const float*)d_in[1];
    const float* Whh  = (const float*)d_in[2];
    const float* bih  = (const float*)d_in[3];
    const float* bhh  = (const float*)d_in[4];

    char* ws = (char*)d_ws;
    _Float16* WPp = (_Float16*)ws;                         //  1 MB
    _Float16* XAe = (_Float16*)(ws + (1ull  << 20));       // 32 MB
    _Float16* XAo = (_Float16*)(ws + (33ull << 20));       // 32 MB
    _Float16* XBe = (_Float16*)(ws + (65ull << 20));       // 16 MB
    _Float16* XBo = (_Float16*)(ws + (81ull << 20));       // 16 MB
    _Float16* H1  = (_Float16*)(ws + (97ull << 20));       // 32 MB
    _Float16* HPb = (_Float16*)(ws + (129ull << 20));      // 16 MB
    float*    BCp = (float*)(ws + (145ull << 20));         //  4 KB

    prepack_weights<<<2049, 256, 0, stream>>>(Wih, Whh, bih, bhh, WPp, BCp);
    convert_split<<<32768, 256, 0, stream>>>(leaf, XAe, XAo);

    _Float16 *XeC = XAe, *XoC = XAo, *XeN = XBe, *XoN = XBo;
    const _Float16* hp = nullptr;
    int M = 65536;
    for (int lev = 0; lev < 12; ++lev) {
        if (M >= 8192) {
            int grid = (M / 128) * 4;
            gru_cell<8, true><<<grid, 256, 0, stream>>>(XeC, hp, WPp, BCp,
                                                        H1, nullptr, nullptr, nullptr, M);
            gru_cell<8, true><<<grid, 256, 0, stream>>>(XoC, H1, WPp, BCp,
                                                        nullptr, XeN, XoN, HPb, M);
        } else {
            int nbm = (M + 63) / 64;
            int grid = nbm * 4;
            if ((nbm & 7) == 0) {
                gru_cell<4, true><<<grid, 256, 0, stream>>>(XeC, hp, WPp, BCp,
                                                            H1, nullptr, nullptr, nullptr, M);
                gru_cell<4, true><<<grid, 256, 0, stream>>>(XoC, H1, WPp, BCp,
                                                            nullptr, XeN, XoN, HPb, M);
            } else {
                gru_cell<4, false><<<grid, 256, 0, stream>>>(XeC, hp, WPp, BCp,
                                                             H1, nullptr, nullptr, nullptr, M);
                gru_cell<4, false><<<grid, 256, 0, stream>>>(XoC, H1, WPp, BCp,
                                                             nullptr, XeN, XoN, HPb, M);
            }
        }
        hp = HPb;
        _Float16* t;
        t = XeC; XeC = XeN; XeN = t;
        t = XoC; XoC = XoN; XoN = t;
        M >>= 1;
    }
    final_out<<<32, 256, 0, stream>>>(XeC, XoC, (float*)d_out);
}

// Round 5
// 702.276 us; speedup vs baseline: 1.8327x; 1.8327x over previous
//
#include <hip/hip_runtime.h>
#include <hip/hip_bf16.h>
#include <stdint.h>

typedef _Float16 f16x8 __attribute__((ext_vector_type(8)));
typedef float    f32x4 __attribute__((ext_vector_type(4)));

// async 16-B global->LDS DMA: per-lane global src, dest = wave-uniform base + lane*16
#define GLDS16(gptr, lptr) \
  __builtin_amdgcn_global_load_lds((const __attribute__((address_space(1))) void*)(gptr), \
                                   (__attribute__((address_space(3))) void*)(lptr), 16, 0, 0)

// WP layout: [c(8)][d0b(4)][g(4)][sub(8)][nl(64)][j(8)] halves.
// element = W(group g, dim d = d0b*64+nl, k = c*64+sub*8+j)
// Block 2048 packs BC[1024]: [d]=bih[d]+bhh[d], [256+d]=bih[256+d]+bhh[256+d],
//                            [512+d]=bih[512+d], [768+d]=bhh[512+d]
__global__ __launch_bounds__(256) void prepack_weights(
    const float* __restrict__ Wih, const float* __restrict__ Whh,
    const float* __restrict__ bih, const float* __restrict__ bhh,
    _Float16* __restrict__ WP, float* __restrict__ BC)
{
    if (blockIdx.x == 2048) {
        int i = threadIdx.x;
        BC[i]       = bih[i] + bhh[i];
        BC[256 + i] = bih[256 + i] + bhh[256 + i];
        BC[512 + i] = bih[512 + i];
        BC[768 + i] = bhh[512 + i];
        return;
    }
    int idx = blockIdx.x * 256 + threadIdx.x;   // 524288 total
    int j   = idx & 7;
    int nl  = (idx >> 3) & 63;
    int sub = (idx >> 9) & 7;
    int g   = (idx >> 12) & 3;
    int d0b = (idx >> 14) & 3;
    int c   = idx >> 16;
    int k = c * 64 + sub * 8 + j;
    int d = d0b * 64 + nl;
    float v = 0.f;
    if (g == 0)      v = (k < 256) ? Wih[d * 256 + k]         : Whh[d * 256 + (k - 256)];
    else if (g == 1) v = (k < 256) ? Wih[(256 + d) * 256 + k] : Whh[(256 + d) * 256 + (k - 256)];
    else if (g == 2) v = (k < 256) ? Wih[(512 + d) * 256 + k] : 0.f;
    else             v = (k >= 256) ? Whh[(512 + d) * 256 + (k - 256)] : 0.f;
    WP[idx] = (_Float16)v;
}

// fp32 leaf -> fp16, split even/odd rows (xL / xR contiguous)
__global__ __launch_bounds__(256) void convert_split(
    const float* __restrict__ leaf, _Float16* __restrict__ XE, _Float16* __restrict__ XO)
{
    int t = blockIdx.x * 256 + threadIdx.x;
    size_t e = (size_t)t * 4;
    int row = (int)(e >> 8), col = (int)(e & 255);
    float4 v = *(const float4*)(leaf + e);
    _Float16* dst = ((row & 1) ? XO : XE) + ((size_t)(row >> 1) * 256 + col);
    union { _Float16 h[4]; uint64_t u; } p;
    p.h[0] = (_Float16)v.x; p.h[1] = (_Float16)v.y;
    p.h[2] = (_Float16)v.z; p.h[3] = (_Float16)v.w;
    *(uint64_t*)dst = p.u;
}

// GRU cell. A and B both staged via async DMA into double-buffered LDS.
// ONE barrier per chunk: barrier -> issue A(c+1),B(c+1) -> compute(c).
// All DMA has a full compute phase to land before its draining barrier.
// cell1 (Hout != null): h' -> Hout[m]        (hin = Hsrc[m] or 0)
// cell2 (Hout == null): E=0.5(hin+h') -> Ee/Eo split; HP[m/2] = pair-avg(h')
template<int MT, bool SWIZ>
__global__ __launch_bounds__(256, (MT == 8) ? 2 : 3) void gru_cell(
    const _Float16* __restrict__ Xsrc,
    const _Float16* __restrict__ Hsrc,
    const _Float16* __restrict__ WP,
    const float* __restrict__ BC,
    _Float16* __restrict__ Hout,
    _Float16* __restrict__ Ee, _Float16* __restrict__ Eo, _Float16* __restrict__ HP,
    int M)
{
    constexpr int AROW = MT * 16 * 8;       // halves per A sub-row (no pad; b128 reads are bank-uniform)
    constexpr int ASZ  = 8 * AROW;          // MT=8: 8 K halves = 16 KB
    constexpr int BROW = 512;               // 64 dims * 8 halves
    constexpr int BSZ  = 3 * 8 * BROW;      // 12 K halves = 24 KB
    __shared__ __align__(16) _Float16 Alds[2 * ASZ];   // MT=8: 32 KB
    __shared__ __align__(16) _Float16 Blds[2 * BSZ];   // 48 KB  (total 80 KB -> 2 blocks/CU)

    const int tid  = threadIdx.x;
    int bm, d0b;
    if (SWIZ) {  // siblings (same bm, 4 d0b) share blockIdx%8 -> same XCD
        int xcd = blockIdx.x & 7, slot = blockIdx.x >> 3;
        d0b = slot & 3;
        bm  = (slot >> 2) * 8 + xcd;
    } else {
        bm = blockIdx.x >> 2; d0b = blockIdx.x & 3;
    }
    const int m0   = bm * (MT * 16);
    const int wave = tid >> 6, lane = tid & 63;
    const int quad = lane >> 4, lo = lane & 15;

    const bool has_h = (Hsrc != nullptr);
    const int nch = has_h ? 8 : 4;

    f32x4 acc[MT][4];
#pragma unroll
    for (int a = 0; a < MT; ++a)
#pragma unroll
        for (int b = 0; b < 4; ++b) acc[a][b] = (f32x4){0.f, 0.f, 0.f, 0.f};
    float hinv[MT][4];

    auto issueB = [&](int c) {   // 24 DMA issues (3 active groups x 8 subs), 6/wave
        const size_t cb = (size_t)(c * 4 + d0b) * 4;
        _Float16* dstb = Blds + (c & 1) * BSZ;
#pragma unroll
        for (int i = 0; i < 6; ++i) {
            int bi = wave * 6 + i;
            int slot = bi >> 3, sub = bi & 7;
            int g = (slot == 2) ? ((c < 4) ? 2 : 3) : slot;
            GLDS16(WP + ((cb + g) * 8 + sub) * 512 + lane * 8,
                   dstb + (slot * 8 + sub) * BROW);
        }
    };

    auto issueA = [&](int c) {   // 2*MT DMA issues, MT/2 per wave
        const _Float16* base = (c < 4) ? Xsrc : Hsrc;
        const int coloff = (c & 3) * 64;
        _Float16* Ab = Alds + (c & 1) * ASZ;
        constexpr int IPS = MT / 4;          // issues per sub-row
#pragma unroll
        for (int i = 0; i < MT / 2; ++i) {
            int ai = wave * (MT / 2) + i;
            int sub = ai / IPS, mh = ai % IPS;
            int row = m0 + mh * 64 + lane;
            if (MT == 4 && row >= M) row = M - 1;   // tail clamp
            GLDS16(base + (size_t)row * 256 + coloff + sub * 8,
                   Ab + sub * AROW + mh * 64 * 8);
        }
    };

    issueB(0);
    issueA(0);

    for (int c = 0; c < nch; ++c) {
        __syncthreads();                  // drains A(c),B(c); frees (c+1)-parity buffers
        if (c + 1 < nch) {
            issueB(c + 1);                // full compute phase in flight
            issueA(c + 1);
        }

        const _Float16* Bb = Blds + (c & 1) * BSZ;
        const _Float16* Ab = Alds + (c & 1) * ASZ;
#pragma unroll
        for (int ks = 0; ks < 2; ++ks) {
            const int subb = ks * 4 + quad;
            const _Float16* brow = Bb + subb * BROW + (wave * 16 + lo) * 8;
            f16x8 b0 = *(const f16x8*)(brow);
            f16x8 b1 = *(const f16x8*)(brow + 8 * BROW);
            f16x8 b2 = *(const f16x8*)(brow + 16 * BROW);
            f16x8 af[MT];
#pragma unroll
            for (int mt = 0; mt < MT; ++mt)
                af[mt] = *(const f16x8*)(Ab + subb * AROW + (mt * 16 + lo) * 8);
#pragma unroll
            for (int mt = 0; mt < MT; ++mt)
                acc[mt][0] = __builtin_amdgcn_mfma_f32_16x16x32_f16(af[mt], b0, acc[mt][0], 0, 0, 0);
#pragma unroll
            for (int mt = 0; mt < MT; ++mt)
                acc[mt][1] = __builtin_amdgcn_mfma_f32_16x16x32_f16(af[mt], b1, acc[mt][1], 0, 0, 0);
            if (c < 4) {
#pragma unroll
                for (int mt = 0; mt < MT; ++mt)
                    acc[mt][2] = __builtin_amdgcn_mfma_f32_16x16x32_f16(af[mt], b2, acc[mt][2], 0, 0, 0);
            } else {
#pragma unroll
                for (int mt = 0; mt < MT; ++mt)
                    acc[mt][3] = __builtin_amdgcn_mfma_f32_16x16x32_f16(af[mt], b2, acc[mt][3], 0, 0, 0);
            }
        }

        // capture hin from LDS while this chunk holds our dim-columns of Hsrc
        if (has_h && c == 4 + d0b) {
            const _Float16* Ab2 = Alds + (c & 1) * ASZ;
            const int colw = wave * 16 + lo;
            const int sub = colw >> 3, j = colw & 7;
#pragma unroll
            for (int mt = 0; mt < MT; ++mt)
#pragma unroll
                for (int r = 0; r < 4; ++r)
                    hinv[mt][r] = (float)Ab2[sub * AROW + (mt * 16 + quad * 4 + r) * 8 + j];
        }
    }

    // ---- epilogue (no global loads) ----
    const int d = d0b * 64 + wave * 16 + lo;
    const float brz0 = BC[d];        // bir+bhr
    const float brz1 = BC[256 + d];  // biz+bhz
    const float bni  = BC[512 + d];  // bin
    const float bnh  = BC[768 + d];  // bhn
#pragma unroll
    for (int mt = 0; mt < MT; ++mt) {
        const int mbase = m0 + mt * 16 + quad * 4;
        float hq[4], h1v[4];
#pragma unroll
        for (int r = 0; r < 4; ++r) {
            float hin = has_h ? hinv[mt][r] : 0.f;
            h1v[r] = hin;
            float rg = 1.f / (1.f + __expf(-(acc[mt][0][r] + brz0)));
            float zg = 1.f / (1.f + __expf(-(acc[mt][1][r] + brz1)));
            float ex = __expf(2.f * (acc[mt][2][r] + bni + rg * (acc[mt][3][r] + bnh)));
            float nv = 1.f - 2.f / (ex + 1.f);
            hq[r] = (1.f - zg) * nv + zg * hin;
        }
        if (Hout) {
#pragma unroll
            for (int r = 0; r < 4; ++r)
                if (MT == 8 || mbase + r < M)
                    Hout[(size_t)(mbase + r) * 256 + d] = (_Float16)hq[r];
        } else {
#pragma unroll
            for (int r = 0; r < 4; ++r) {
                int m = mbase + r;
                if (MT == 8 || m < M)
                    (((m & 1) ? Eo : Ee))[(size_t)(m >> 1) * 256 + d] =
                        (_Float16)(0.5f * (h1v[r] + hq[r]));
            }
            if (MT == 8 || mbase + 1 < M)
                HP[(size_t)(mbase >> 1) * 256 + d] = (_Float16)(0.5f * (hq[0] + hq[1]));
            if (MT == 8 || mbase + 3 < M)
                HP[(size_t)((mbase >> 1) + 1) * 256 + d] = (_Float16)(0.5f * (hq[2] + hq[3]));
        }
    }
}

__global__ __launch_bounds__(256) void final_out(
    const _Float16* __restrict__ XE, const _Float16* __restrict__ XO,
    float* __restrict__ out)
{
    int i = blockIdx.x * 256 + threadIdx.x;   // 8192
    int j = i >> 8, col = i & 255;
    const _Float16* src = (j & 1) ? XO : XE;
    out[i] = (float)src[(size_t)(j >> 1) * 256 + col];
}

extern "C" void kernel_launch(void* const* d_in, const int* in_sizes, int n_in,
                              void* d_out, int out_size, void* d_ws, size_t ws_size,
                              hipStream_t stream) {
    const float* leaf = (const float*)d_in[0];
    const float* Wih  = (const float*)d_in[1];
    const float* Whh  = (const float*)d_in[2];
    const float* bih  = (const float*)d_in[3];
    const float* bhh  = (const float*)d_in[4];

    char* ws = (char*)d_ws;
    _Float16* WPp = (_Float16*)ws;                         //  1 MB
    _Float16* XAe = (_Float16*)(ws + (1ull  << 20));       // 32 MB
    _Float16* XAo = (_Float16*)(ws + (33ull << 20));       // 32 MB
    _Float16* XBe = (_Float16*)(ws + (65ull << 20));       // 16 MB
    _Float16* XBo = (_Float16*)(ws + (81ull << 20));       // 16 MB
    _Float16* H1  = (_Float16*)(ws + (97ull << 20));       // 32 MB
    _Float16* HPb = (_Float16*)(ws + (129ull << 20));      // 16 MB
    float*    BCp = (float*)(ws + (145ull << 20));         //  4 KB

    prepack_weights<<<2049, 256, 0, stream>>>(Wih, Whh, bih, bhh, WPp, BCp);
    convert_split<<<32768, 256, 0, stream>>>(leaf, XAe, XAo);

    _Float16 *XeC = XAe, *XoC = XAo, *XeN = XBe, *XoN = XBo;
    const _Float16* hp = nullptr;
    int M = 65536;
    for (int lev = 0; lev < 12; ++lev) {
        if (M >= 8192) {
            int grid = (M / 128) * 4;
            gru_cell<8, true><<<grid, 256, 0, stream>>>(XeC, hp, WPp, BCp,
                                                        H1, nullptr, nullptr, nullptr, M);
            gru_cell<8, true><<<grid, 256, 0, stream>>>(XoC, H1, WPp, BCp,
                                                        nullptr, XeN, XoN, HPb, M);
        } else {
            int nbm = (M + 63) / 64;
            int grid = nbm * 4;
            if ((nbm & 7) == 0) {
                gru_cell<4, true><<<grid, 256, 0, stream>>>(XeC, hp, WPp, BCp,
                                                            H1, nullptr, nullptr, nullptr, M);
                gru_cell<4, true><<<grid, 256, 0, stream>>>(XoC, H1, WPp, BCp,
                                                            nullptr, XeN, XoN, HPb, M);
            } else {
                gru_cell<4, false><<<grid, 256, 0, stream>>>(XeC, hp, WPp, BCp,
                                                             H1, nullptr, nullptr, nullptr, M);
                gru_cell<4, false><<<grid, 256, 0, stream>>>(XoC, H1, WPp, BCp,
                                                             nullptr, XeN, XoN, HPb, M);
            }
        }
        hp = HPb;
        _Float16* t;
        t = XeC; XeC = XeN; XeN = t;
        t = XoC; XoC = XoN; XoN = t;
        M >>= 1;
    }
    final_out<<<32, 256, 0, stream>>>(XeC, XoC, (float*)d_out);
}